// Round 6
// baseline (288.241 us; speedup 1.0000x reference)
//
#include <hip/hip_runtime.h>
#include <hip/hip_bf16.h>
#include <stdint.h>

#define LQ 1024
#define BQ 2
#define AQ 14
#define KQ 30
#define EFQ 128
#define EDGE_IN 3152
#define KPAD 3200
#define NCHUNK 50
#define MTILE 128
#define ROWS (BQ*LQ*KQ)            /* 61440 */
#define EIDX_OFF (ROWS*EFQ)        /* 7864320 */

typedef __attribute__((ext_vector_type(8))) _Float16 half8;
typedef __attribute__((ext_vector_type(2))) _Float16 half2t;
typedef __attribute__((ext_vector_type(4))) float floatx4;
typedef unsigned long long ull;

static __device__ __forceinline__ uint32_t pkh(float a, float b) {
    auto h = __builtin_amdgcn_cvt_pkrtz(a, b);   // __fp16 ext_vector(2)
    return __builtin_bit_cast(uint32_t, h);
}
static __device__ __forceinline__ ull umin64(ull a, ull b) { return a < b ? a : b; }

// ---------------------------------------------------------------------------
// Kernel A v6 (unchanged): blocks 0..255 topk (8 rows/block, one wave per row,
// u64-packed keys); blocks 256..305: W fp32 -> f16 padded copy.
// ---------------------------------------------------------------------------
__global__ __launch_bounds__(512) void topk_kernel(
    const float* __restrict__ X, const float* __restrict__ mask,
    const float* __restrict__ W, float* __restrict__ out,
    int* __restrict__ idx_ws, _Float16* __restrict__ wpad)
{
    __shared__ float xs[LQ], ys[LQ], zs[LQ], ms[LQ];
    const int t = threadIdx.x;

    if (blockIdx.x >= 256) {                    // ---- merged wpad ----
        int base = (blockIdx.x - 256)*8192 + t; // 50 blocks x 8192 = 409600 exact
        #pragma unroll
        for (int r = 0; r < 16; ++r) {
            int idx = base + r*512;
            int n = idx / KPAD, f = idx - n*KPAD;
            float v = (f < EDGE_IN) ? W[(size_t)n*EDGE_IN + f] : 0.0f;
            wpad[idx] = (_Float16)v;
        }
        return;
    }

    const int w = t >> 6, lane = t & 63;
    const int row = blockIdx.x*8 + w;           // same b for whole block
    const int b = row >> 10, i = row & (LQ - 1);

    for (int j = t; j < LQ; j += 512) {
        size_t base = ((size_t)(b*LQ + j))*42 + 3;   // atom 1 (CA)
        xs[j] = X[base+0]; ys[j] = X[base+1]; zs[j] = X[base+2];
        ms[j] = mask[b*LQ + j];
    }
    __syncthreads();

    const float mif = ms[i];
    const double cx = (double)xs[i], cy = (double)ys[i], cz = (double)zs[i];

    double Dk[16]; float mf[16];
    bool allone = (mif == 1.0f);
    #pragma unroll
    for (int s = 0; s < 16; ++s) {
        int j = s*64 + lane;
        double dx = __dsub_rn(cx, (double)xs[j]);
        double dy = __dsub_rn(cy, (double)ys[j]);
        double dz = __dsub_rn(cz, (double)zs[j]);
        mf[s] = ms[j];
        Dk[s] = __dadd_rn(__dadd_rn(__dmul_rn(dx,dx), __dmul_rn(dy,dy)),
                          __dmul_rn(dz,dz));
        allone = allone && (mf[s] == 1.0f);
    }

    if (!__all(allone ? 1 : 0)) {
        // exact general path: D = mi*mj*sqrt(ssq+1e-6); key = D + 2(1-m2)*max(D)
        const double mi_d = (double)mif;
        double lm = 0.0;
        #pragma unroll
        for (int s = 0; s < 16; ++s) {
            double m2 = __dmul_rn(mi_d, (double)mf[s]);
            Dk[s] = __dmul_rn(m2, sqrt(__dadd_rn(Dk[s], 1e-6)));
            lm = fmax(lm, Dk[s]);
        }
        #pragma unroll
        for (int off = 32; off; off >>= 1) lm = fmax(lm, __shfl_xor(lm, off));
        #pragma unroll
        for (int s = 0; s < 16; ++s) {
            double m2 = __dmul_rn(mi_d, (double)mf[s]);
            Dk[s] = __dadd_rn(Dk[s],
                    __dmul_rn(__dmul_rn(2.0, __dsub_rn(1.0, m2)), lm));
        }
    }

    ull key[16];
    #pragma unroll
    for (int s = 0; s < 16; ++s)
        key[s] = (((ull)__double_as_longlong(Dk[s])) & ~1023ull)
               | (unsigned)(s*64 + lane);

    for (int k = 0; k < KQ; ++k) {
        ull a0 = umin64(key[0],  key[1]),  a1 = umin64(key[2],  key[3]);
        ull a2 = umin64(key[4],  key[5]),  a3 = umin64(key[6],  key[7]);
        ull a4 = umin64(key[8],  key[9]),  a5 = umin64(key[10], key[11]);
        ull a6 = umin64(key[12], key[13]), a7 = umin64(key[14], key[15]);
        ull b0 = umin64(a0, a1), b1 = umin64(a2, a3);
        ull b2 = umin64(a4, a5), b3 = umin64(a6, a7);
        ull bk = umin64(umin64(b0, b1), umin64(b2, b3));
        #pragma unroll
        for (int off = 32; off; off >>= 1)
            bk = umin64(bk, (ull)__shfl_xor(bk, off));
        int j = (int)(bk & 1023ull);
        if (lane == 0) {
            int rg = row*KQ + k;
            idx_ws[rg] = j;
            out[EIDX_OFF + rg] = (float)j;
        }
        bool mine = ((j & 63) == lane);
        int s_win = j >> 6;
        #pragma unroll
        for (int s = 0; s < 16; ++s)
            key[s] = (mine && s == s_win) ? ~0ull : key[s];
    }
}

// ---------------------------------------------------------------------------
// Kernel B v13 = v12 + B-operand split across pipes (LDS was ~96% busy):
//  - k-half 0..31 of each chunk staged in LDS (dbuf 2x8KB, paired-row XOR
//    swizzle, one 16B global_load_lds per thread per chunk)
//  - k-half 32..63 read DIRECT from L2 (wpad is 770KB, XCD-L2-resident) into
//    registers, issued at chunk top, consumed after gen + pass-1 MFMAs
//  -> B LDS reads halve (8 b128/thread-chunk), stage DMA halves, LDS 47.6KB.
//  MFMA split into pass-1 (b0, LDS) then pass-2 (b1, regs); per-acc k-order
//  unchanged -> numerics identical to v12.
// ---------------------------------------------------------------------------
struct FusedSmem {
    alignas(16) unsigned short atoms[256*56];  // 28672 B (scaled+poisoned f16)
    alignas(16) unsigned short Bl[2*4096];     // 16384 B: dbuf k-half chunk
    alignas(16) float drow[MTILE];             // 512
    int residg[256];                           // 1024
    float gsh[EFQ], bsh[EFQ];                  // 1024
};                                             // 47,616 B

// RBF features [8] for one (center-atom, neighbor-atom) pair, rbase folded
// into rboff. Poisoned coords (+/-30000) make all eight exp2 give exact +0.
static __device__ __forceinline__ void gen_rbf(
    const char* __restrict__ rowA, const char* __restrict__ rowB,
    int ao, int bo, float rboff, uint32_t* __restrict__ v)
{
    uint2 ca = *reinterpret_cast<const uint2*>(rowA + ao);
    uint2 nb = *reinterpret_cast<const uint2*>(rowB + bo);
    half2t c0 = __builtin_bit_cast(half2t, ca.x);
    half2t c1 = __builtin_bit_cast(half2t, ca.y);
    half2t n0 = __builtin_bit_cast(half2t, nb.x);
    half2t n1 = __builtin_bit_cast(half2t, nb.y);
    half2t dxy = c0 - n0;                        // v_pk_add_f16
    half2t dzw = c1 - n1;
    float dx = (float)dxy[0], dy = (float)dxy[1], dz = (float)dzw[0];
    float ssq = __fmaf_rn(dx, dx, __fmaf_rn(dy, dy,
                __fmaf_rn(dz, dz, 9.2332585e-7f)));     // (1e-6 scaled)
    float u = __builtin_amdgcn_sqrtf(ssq) + rboff;
    const float CJ[8] = {0.0f, 1.28119795f, 2.5623959f, 3.84359385f,
                         5.1247918f, 6.40598975f, 7.6871877f, 8.96838565f};
    #pragma unroll
    for (int k = 0; k < 4; ++k) {
        float t0 = u - CJ[2*k];
        float t1 = u - CJ[2*k+1];
        v[k] = pkh(__builtin_amdgcn_exp2f(-(t0*t0)),
                   __builtin_amdgcn_exp2f(-(t1*t1)));
    }
}

__global__ __launch_bounds__(512) void fused_kernel(
    const float* __restrict__ X, const float* __restrict__ atom_mask,
    const _Float16* __restrict__ wpad, const float* __restrict__ gamma,
    const float* __restrict__ beta, const int* __restrict__ idx_ws,
    float* __restrict__ out)
{
    __shared__ FusedSmem sm;
    const int t = threadIdx.x;               // 0..511
    const int row0 = blockIdx.x * MTILE;
    const int b = row0 / (LQ*KQ);            // tiles never straddle b (30720 % 128 == 0)

    if (t < MTILE) {
        int rg = row0 + t;
        int rem = rg - b*(LQ*KQ);
        int i = rem / KQ;
        int j = idx_ws[rg];
        sm.residg[t]       = b*LQ + i;
        sm.residg[MTILE+t] = b*LQ + j;
        sm.drow[t] = (float)j - (float)i;
    }
    if (t < EFQ) { sm.gsh[t] = gamma[t]; sm.bsh[t] = beta[t]; }
    __syncthreads();

    const int w = t >> 6, lane = t & 63, q = lane >> 4, l15 = lane & 15;
    const int m = w*16 + l15;                 // tile-local row (0..127)

    // ---- B LDS staging: k-half 0..31, one 16B unit per thread ------------
    // Physical: 64 rows x 128B, linear dst (r = t>>3, slot = t&7).
    // Logical (n, kslot) at slot ((n&1)*4 + kslot) ^ (r&7), n = 2r + hi.
    // Source pre-swizzled so linear dst receives the right data (v7 pattern).
    {
        // nothing: hoists below
    }
    const int scomb = (t & 7) ^ ((t >> 3) & 7);
    const int sn    = (((t >> 3)) << 1) | (scomb >> 2);
    const _Float16* stSrc = wpad + (size_t)sn*KPAD + (scomb & 3)*8;
    auto stage = [&](int c) {
        __builtin_amdgcn_global_load_lds(
            (const __attribute__((address_space(1))) uint32_t*)(stSrc + c*64),
            (__attribute__((address_space(3))) uint32_t*)
                &sm.Bl[((c & 1) << 12) + (t << 3)],
            16, 0, 0);
    };
    stage(0);                                 // flies across the prologue

    // stage atoms: fp32 global -> packed f16 LDS (raw, x,y,z,0 per slot)
    for (int u2 = t; u2 < 256*14; u2 += 512) {   // 7 exact iterations
        int s = u2 / 14; int a = u2 - s*14;
        const float* xp = X + (size_t)sm.residg[s]*42 + a*3;
        uint2 pk; pk.x = pkh(xp[0], xp[1]); pk.y = pkh(xp[2], 0.0f);
        *reinterpret_cast<uint2*>(&sm.atoms[s*56 + a*4]) = pk;
    }
    __syncthreads();

    if (t < 256) {   // Cb (raw) into slot 4, then scale + mask-poison all 14
        unsigned short* at = &sm.atoms[t*56];
        auto ld3 = [&](int slot, float& x, float& y, float& z) {
            half2t p0 = *reinterpret_cast<const half2t*>(at + slot*4);
            half2t p1 = *reinterpret_cast<const half2t*>(at + slot*4 + 2);
            x = (float)p0[0]; y = (float)p0[1]; z = (float)p1[0];
        };
        float Nx,Ny,Nz, Cax,Cay,Caz, Cx,Cy,Cz;
        ld3(0, Nx,Ny,Nz); ld3(1, Cax,Cay,Caz); ld3(2, Cx,Cy,Cz);
        float bx=Cax-Nx, by=Cay-Ny, bz=Caz-Nz;
        float ex=Cx-Cax, ey=Cy-Cay, ez=Cz-Caz;
        float ax = by*ez - bz*ey, ay = bz*ex - bx*ez, az = bx*ey - by*ex;
        float cbx = -0.58273431f*ax + 0.56802827f*bx - 0.54067466f*ex + Cax;
        float cby = -0.58273431f*ay + 0.56802827f*by - 0.54067466f*ey + Cay;
        float cbz = -0.58273431f*az + 0.56802827f*bz - 0.54067466f*ez + Caz;
        uint2 pk4; pk4.x = pkh(cbx, cby); pk4.y = pkh(cbz, 0.0f);
        *reinterpret_cast<uint2*>(at + 4*4) = pk4;   // slot 4 = Cb (raw)

        const float P = (t < MTILE) ? 30000.0f : -30000.0f;  // center/neighbor
        const uint32_t pxx = pkh(P, P), pxy = pkh(P, 0.0f);
        half2t sc2; sc2[0] = (_Float16)0.96089846f; sc2[1] = (_Float16)0.96089846f;
        const float* amp = &atom_mask[(size_t)sm.residg[t]*AQ];
        #pragma unroll
        for (int a = 0; a < AQ; ++a) {
            uint2 vv = *reinterpret_cast<const uint2*>(at + a*4);
            half2t lo = __builtin_bit_cast(half2t, vv.x) * sc2;
            half2t hi = __builtin_bit_cast(half2t, vv.y) * sc2;
            bool msk = amp[a] > 0.5f;
            uint2 ov;
            ov.x = msk ? pxx : __builtin_bit_cast(uint32_t, lo);
            ov.y = msk ? pxy : __builtin_bit_cast(uint32_t, hi);
            *reinterpret_cast<uint2*>(at + a*4) = ov;
        }
    }

    // ---- b0 LDS read base: (n = nt*16+l15, kslot q) -> shorts offset
    //   (nt*8 + (l15>>1))*64 + (((l15&1)<<2 | q) ^ (l15>>1))*8
    const int bbase = (l15 >> 1)*64 + ((((((l15 & 1) << 2) | q)) ^ (l15 >> 1)) << 3);

    // ---- b1 direct-L2 base pointers: n = nt*16 + l15, k = 32 + q*8
    const _Float16* bg = wpad + (size_t)l15*KPAD + 32 + q*8;
    const _Float16* bgp[8];
    #pragma unroll
    for (int nt = 0; nt < 8; ++nt) bgp[nt] = bg + (size_t)nt*(16*KPAD);

    const char* rowA = (const char*)&sm.atoms[m*56];
    const char* rowB = (const char*)&sm.atoms[(MTILE+m)*56];
    const int   qlt2  = (q < 2) ? 1 : 0;
    const float rboff = -(float)((q & 1) * 8) * 1.28119795f;

    floatx4 acc[8];
    #pragma unroll
    for (int nt = 0; nt < 8; ++nt) acc[nt] = (floatx4){0.f,0.f,0.f,0.f};

    __syncthreads();   // atoms scaled/poisoned visible; stage(0) drained

    union H8 { uint32_t u[4]; half8 h; };
    for (int c = 0; c < NCHUNK; ++c) {
        // issue this chunk's b1 L2 loads first (latency hidden under gen+pass1)
        half8 b1r[8];
        #pragma unroll
        for (int nt = 0; nt < 8; ++nt)
            b1r[nt] = *reinterpret_cast<const half8*>(bgp[nt] + c*64);
        if (c < NCHUNK-1) stage(c+1);         // dbuf DMA, lands by bottom barrier

        // pair addressing: p0 = 4c - (q<2), p1 = p0 + 2; a = p/14, bp = p%14
        int p0 = 4*c - qlt2;
        int p1 = p0 + 2;
        int pa0 = (p0 * 74899) >> 20;  int pa1 = (p1 * 74899) >> 20;
        pa0 = pa0 > 13 ? 13 : pa0;     pa1 = pa1 > 13 ? 13 : pa1;
        int ao0 = pa0 << 3, bo0 = (p0 - pa0*14) << 3;
        int ao1 = pa1 << 3, bo1 = (p1 - pa1*14) << 3;

        H8 a00, a01;
        if (c == 0) {
            if (qlt2) {                        // positional features (f0 = 0 or 8)
                const float fr[8] = {1.0f, 0.31622776601683794f, 0.1f,
                    0.031622776601683794f, 0.01f, 0.0031622776601683794f,
                    0.001f, 0.00031622776601683794f};
                float dr = sm.drow[m];
                float e[8];
                if (q == 0) {
                    #pragma unroll
                    for (int j = 0; j < 8; ++j) e[j] = __cosf(dr * fr[j]);
                } else {
                    #pragma unroll
                    for (int j = 0; j < 8; ++j) e[j] = __sinf(dr * fr[j]);
                }
                #pragma unroll
                for (int k = 0; k < 4; ++k) a00.u[k] = pkh(e[2*k], e[2*k+1]);
            } else {
                gen_rbf(rowA, rowB, ao0, bo0, rboff, a00.u);
            }
        } else {
            gen_rbf(rowA, rowB, ao0, bo0, rboff, a00.u);
        }
        gen_rbf(rowA, rowB, ao1, bo1, rboff, a01.u);

        const unsigned short* Bb = &sm.Bl[(c & 1) << 12];
        #pragma unroll
        for (int nt = 0; nt < 8; ++nt) {       // pass 1: k 0..31 from LDS
            half8 b0 = *reinterpret_cast<const half8*>(&Bb[nt*512 + bbase]);
            acc[nt] = __builtin_amdgcn_mfma_f32_16x16x32_f16(a00.h, b0, acc[nt], 0, 0, 0);
        }
        #pragma unroll
        for (int nt = 0; nt < 8; ++nt)         // pass 2: k 32..63 from regs
            acc[nt] = __builtin_amdgcn_mfma_f32_16x16x32_f16(a01.h, b1r[nt], acc[nt], 0, 0, 0);

        __syncthreads();   // drains stage DMA; fences Bl[c&1] reads before restage
    }

    // LayerNorm epilogue. C/D layout: col = lane&15, row = quad*4 + reg.
    #pragma unroll
    for (int v = 0; v < 4; ++v) {
        float s = 0.f, s2 = 0.f;
        #pragma unroll
        for (int nt = 0; nt < 8; ++nt) { float x = acc[nt][v]; s += x; s2 += x*x; }
        #pragma unroll
        for (int off = 1; off < 16; off <<= 1) {
            s  += __shfl_xor(s,  off);
            s2 += __shfl_xor(s2, off);
        }
        float mean = s * (1.0f/128.0f);
        float var  = s2 * (1.0f/128.0f) - mean*mean;
        float rstd = 1.0f / sqrtf(var + 1e-5f);
        int row_l = w*16 + q*4 + v;
        size_t obase = (size_t)(row0 + row_l)*EFQ;
        #pragma unroll
        for (int nt = 0; nt < 8; ++nt) {
            int col = nt*16 + l15;
            out[obase + col] = (acc[nt][v] - mean)*rstd*sm.gsh[col] + sm.bsh[col];
        }
    }
}

extern "C" void kernel_launch(void* const* d_in, const int* in_sizes, int n_in,
                              void* d_out, int out_size, void* d_ws, size_t ws_size,
                              hipStream_t stream)
{
    const float* X         = (const float*)d_in[0];
    const float* mask      = (const float*)d_in[1];
    // d_in[2] residue_idx, d_in[3] chain_labels: unused by the reference math
    const float* atom_mask = (const float*)d_in[4];
    const float* W         = (const float*)d_in[5];
    const float* gamma     = (const float*)d_in[6];
    const float* beta      = (const float*)d_in[7];
    float* out = (float*)d_out;

    int*       idx_ws = (int*)d_ws;                               // 61440*4 B
    _Float16*  wpad   = (_Float16*)((char*)d_ws + 262144);        // 128*3200*2 B

    hipLaunchKernelGGL(topk_kernel, dim3(306), dim3(512), 0, stream,
                       X, mask, W, out, idx_ws, wpad);
    hipLaunchKernelGGL(fused_kernel, dim3(ROWS/MTILE), dim3(512), 0, stream,
                       X, atom_mask, wpad, gamma, beta, idx_ws, out);
}